// Round 1
// baseline (583.110 us; speedup 1.0000x reference)
//
#include <hip/hip_runtime.h>
#include <math.h>

#define C_CLASSES 100000
#define FEAT      512
#define BATCH_N   32768
#define EPS_N     1e-12f

// ---------------- Kernel A: per-row normalize-accumulate + copy-out ----------------
// Each block grid-strides over center rows. For each row (512 floats, 256 thr x float2):
//   - compute sum of squares (wave shuffle + LDS across 4 waves)
//   - accumulate centers[row]*rnorm into per-block LDS accumulator [512]
//   - copy raw row to out_centers (d_out+1; 4B-aligned only -> scalar stores)
// Then write the block's partial mean-accumulator to cpart[block*512 + j].
__global__ void __launch_bounds__(256) centers_pass(
    const float* __restrict__ centers,
    float* __restrict__ out_centers,   // d_out + 1
    float* __restrict__ cpart)         // [gridDim.x * 512]
{
    __shared__ float2 acc[256];
    __shared__ float wsum[4];
    __shared__ float totsh;

    const int t = threadIdx.x;
    acc[t] = make_float2(0.f, 0.f);
    __syncthreads();

    const int wid = t >> 6;
    const int ln  = t & 63;

    for (int row = blockIdx.x; row < C_CLASSES; row += gridDim.x) {
        const size_t base = (size_t)row * FEAT + 2 * t;
        const float2 v = *reinterpret_cast<const float2*>(centers + base);

        float ss = v.x * v.x + v.y * v.y;
        #pragma unroll
        for (int o = 32; o > 0; o >>= 1) ss += __shfl_down(ss, o, 64);
        if (ln == 0) wsum[wid] = ss;
        __syncthreads();
        if (t == 0) totsh = wsum[0] + wsum[1] + wsum[2] + wsum[3];
        __syncthreads();

        const float rn = 1.f / fmaxf(sqrtf(totsh), EPS_N);
        float2 a = acc[t];
        a.x += v.x * rn;
        a.y += v.y * rn;
        acc[t] = a;

        // raw copy (dst misaligned by 1 float globally -> scalar dword stores)
        out_centers[base]     = v.x;
        out_centers[base + 1] = v.y;
    }

    const float2 a = acc[t];
    cpart[(size_t)blockIdx.x * FEAT + 2 * t]     = a.x;
    cpart[(size_t)blockIdx.x * FEAT + 2 * t + 1] = a.y;
}

// ---------------- Kernel B: reduce block partials -> mean[512] ----------------
__global__ void reduce_mean(const float* __restrict__ cpart, int nblk,
                            float* __restrict__ mean)
{
    const int j = blockIdx.x * blockDim.x + threadIdx.x;
    if (j < FEAT) {
        float s = 0.f;
        for (int b = 0; b < nblk; ++b) s += cpart[(size_t)b * FEAT + j];
        mean[j] = s / (float)C_CLASSES;
    }
}

// ---------------- Kernel C: per-x-row loss terms (one wave per row) ----------------
__global__ void __launch_bounds__(256) row_loss(
    const float* __restrict__ x,
    const int*   __restrict__ labels,
    const float* __restrict__ centers,
    const float* __restrict__ mean,
    float* __restrict__ lpart)          // [gridDim.x * 2]
{
    const int wid = threadIdx.x >> 6;
    const int ln  = threadIdx.x & 63;
    const int row = blockIdx.x * 4 + wid;

    const float4* __restrict__ xr = reinterpret_cast<const float4*>(x + (size_t)row * FEAT);
    const float4* __restrict__ mr = reinterpret_cast<const float4*>(mean);
    const int lab = labels[row];
    const float4* __restrict__ cr = reinterpret_cast<const float4*>(centers + (size_t)lab * FEAT);

    float ssx = 0.f, dxm = 0.f, ssc = 0.f, dxc = 0.f;
    #pragma unroll
    for (int k = 0; k < 2; ++k) {
        const float4 xv = xr[ln * 2 + k];
        const float4 mv = mr[ln * 2 + k];
        const float4 cv = cr[ln * 2 + k];
        ssx += xv.x * xv.x + xv.y * xv.y + xv.z * xv.z + xv.w * xv.w;
        dxm += xv.x * mv.x + xv.y * mv.y + xv.z * mv.z + xv.w * mv.w;
        ssc += cv.x * cv.x + cv.y * cv.y + cv.z * cv.z + cv.w * cv.w;
        dxc += xv.x * cv.x + xv.y * cv.y + xv.z * cv.z + xv.w * cv.w;
    }

    #pragma unroll
    for (int o = 32; o > 0; o >>= 1) {
        ssx += __shfl_down(ssx, o, 64);
        dxm += __shfl_down(dxm, o, 64);
        ssc += __shfl_down(ssc, o, 64);
        dxc += __shfl_down(dxc, o, 64);
    }

    __shared__ float t1s[4], t2s[4];
    if (ln == 0) {
        const float rnx = 1.f / fmaxf(sqrtf(ssx), EPS_N);
        const float rnc = 1.f / fmaxf(sqrtf(ssc), EPS_N);
        const float s_all = dxm * rnx;
        const float s_lab = dxc * rnx * rnc;
        const float e_all = expf(s_all);
        const float kC    = (float)((double)(C_CLASSES + 1) / (double)C_CLASSES);
        const float t1 = (e_all - expf(s_lab * kC));                        // / ALPHA1 (=1)
        const float t2 = -fabsf((e_all - expf(s_lab) + 0.2f) * (1.f / 50.f));
        t1s[wid] = t1;
        t2s[wid] = t2;
    }
    __syncthreads();
    if (threadIdx.x == 0) {
        lpart[(size_t)blockIdx.x * 2]     = t1s[0] + t1s[1] + t1s[2] + t1s[3];
        lpart[(size_t)blockIdx.x * 2 + 1] = t2s[0] + t2s[1] + t2s[2] + t2s[3];
    }
}

// ---------------- Kernel D: final reduction + blend ----------------
__global__ void final_loss(const float* __restrict__ lpart, int n,
                           const int* __restrict__ epoch,
                           float* __restrict__ out)
{
    __shared__ double sh1[256];
    __shared__ double sh2[256];
    double s1 = 0.0, s2 = 0.0;
    for (int i = threadIdx.x; i < n; i += blockDim.x) {
        s1 += (double)lpart[(size_t)i * 2];
        s2 += (double)lpart[(size_t)i * 2 + 1];
    }
    sh1[threadIdx.x] = s1;
    sh2[threadIdx.x] = s2;
    __syncthreads();
    for (int s = 128; s > 0; s >>= 1) {
        if (threadIdx.x < s) {
            sh1[threadIdx.x] += sh1[threadIdx.x + s];
            sh2[threadIdx.x] += sh2[threadIdx.x + s];
        }
        __syncthreads();
    }
    if (threadIdx.x == 0) {
        const float v  = fminf((float)(*epoch) * (1.f / 14.f), 1.f);
        const float l1 = (float)(sh1[0] / (double)BATCH_N);
        const float l2 = (float)(sh2[0] / (double)BATCH_N);
        out[0] = (1.f - v) * l1 + v * l2;
    }
}

extern "C" void kernel_launch(void* const* d_in, const int* in_sizes, int n_in,
                              void* d_out, int out_size, void* d_ws, size_t ws_size,
                              hipStream_t stream)
{
    const float* x       = (const float*)d_in[0];
    const int*   labels  = (const int*)d_in[1];
    // d_in[2] = ori_labels (unused by reference)
    const int*   epoch   = (const int*)d_in[3];
    const float* centers = (const float*)d_in[4];
    float* out = (float*)d_out;

    float* ws    = (float*)d_ws;
    float* mean  = ws;                      // 512 floats
    float* lpart = ws + 1024;               // (BATCH_N/4)*2 = 16384 floats
    float* cpart = ws + 1024 + 16384;       // nblkA * 512 floats

    const size_t fixed_bytes = (size_t)(1024 + 16384) * sizeof(float);
    int nblkA = 2048;
    if (ws_size < fixed_bytes + (size_t)nblkA * FEAT * sizeof(float)) {
        size_t avail = (ws_size > fixed_bytes) ? (ws_size - fixed_bytes) : 0;
        nblkA = (int)(avail / (FEAT * sizeof(float)));
        if (nblkA < 1) nblkA = 1;
    }

    centers_pass<<<nblkA, 256, 0, stream>>>(centers, out + 1, cpart);
    reduce_mean<<<2, 256, 0, stream>>>(cpart, nblkA, mean);
    row_loss<<<BATCH_N / 4, 256, 0, stream>>>(x, labels, centers, mean, lpart);
    final_loss<<<1, 256, 0, stream>>>(lpart, BATCH_N / 4, epoch, out);
}

// Round 2
// 133.787 us; speedup vs baseline: 4.3585x; 4.3585x over previous
//
#include <hip/hip_runtime.h>
#include <math.h>

#define C_CLASSES 100000
#define FEAT      512
#define BATCH_N   32768
#define EPS_N     1e-12f

// ---------------- Kernel A: wave-per-row normalize-accumulate + copy-out ----------------
// Each wave owns rows (blockIdx*4 + wid, stride gridDim*4). Per row:
//   - two float4 loads per lane (fully coalesced: [ln*4, ln*4+256))
//   - sum-of-squares via xor-shuffle butterfly (no LDS, no barriers in loop)
//   - accumulate normalized values into per-lane registers
//   - copy raw row to out_centers (d_out+1, 4B-aligned only -> scalar stores)
// End: combine the 4 waves' accumulators via LDS, write block partial.
__global__ void __launch_bounds__(256) centers_pass(
    const float* __restrict__ centers,
    float* __restrict__ out_centers,   // d_out + 1
    float* __restrict__ cpart)         // [gridDim.x * 512]
{
    const int t   = threadIdx.x;
    const int wid = t >> 6;
    const int ln  = t & 63;

    float acc[2][4] = {{0.f,0.f,0.f,0.f},{0.f,0.f,0.f,0.f}};

    for (int row = blockIdx.x * 4 + wid; row < C_CLASSES; row += gridDim.x * 4) {
        const float* rp = centers + (size_t)row * FEAT;
        float4 v0 = *reinterpret_cast<const float4*>(rp + ln * 4);
        float4 v1 = *reinterpret_cast<const float4*>(rp + 256 + ln * 4);

        float ss = v0.x*v0.x + v0.y*v0.y + v0.z*v0.z + v0.w*v0.w
                 + v1.x*v1.x + v1.y*v1.y + v1.z*v1.z + v1.w*v1.w;
        #pragma unroll
        for (int o = 32; o > 0; o >>= 1) ss += __shfl_xor(ss, o, 64);

        const float rn = 1.f / fmaxf(sqrtf(ss), EPS_N);
        acc[0][0] += v0.x * rn; acc[0][1] += v0.y * rn;
        acc[0][2] += v0.z * rn; acc[0][3] += v0.w * rn;
        acc[1][0] += v1.x * rn; acc[1][1] += v1.y * rn;
        acc[1][2] += v1.z * rn; acc[1][3] += v1.w * rn;

        float* op = out_centers + (size_t)row * FEAT;
        op[ln*4 + 0] = v0.x; op[ln*4 + 1] = v0.y;
        op[ln*4 + 2] = v0.z; op[ln*4 + 3] = v0.w;
        op[256 + ln*4 + 0] = v1.x; op[256 + ln*4 + 1] = v1.y;
        op[256 + ln*4 + 2] = v1.z; op[256 + ln*4 + 3] = v1.w;
    }

    __shared__ float accsh[4][FEAT];
    #pragma unroll
    for (int k = 0; k < 2; ++k)
        #pragma unroll
        for (int c = 0; c < 4; ++c)
            accsh[wid][k*256 + ln*4 + c] = acc[k][c];
    __syncthreads();

    #pragma unroll
    for (int j = t; j < FEAT; j += 256)
        cpart[(size_t)blockIdx.x * FEAT + j] =
            accsh[0][j] + accsh[1][j] + accsh[2][j] + accsh[3][j];
}

// ---------------- Kernel B1: parallel partial reduce over cpart blocks ----------------
// Block p sums rows b = p, p+32, ... of cpart (each iteration: 512 threads read
// one contiguous 2KB row -> fully coalesced). Writes partial2[p][512].
__global__ void __launch_bounds__(512) reduce_mean_s1(
    const float* __restrict__ cpart, int nblk,
    float* __restrict__ partial2)
{
    const int j = threadIdx.x;             // feature
    float s = 0.f;
    for (int b = blockIdx.x; b < nblk; b += gridDim.x)
        s += cpart[(size_t)b * FEAT + j];
    partial2[(size_t)blockIdx.x * FEAT + j] = s;
}

// ---------------- Kernel B2: finish -> mean[512] ----------------
__global__ void __launch_bounds__(512) reduce_mean_s2(
    const float* __restrict__ partial2, int np,
    float* __restrict__ mean)
{
    const int j = threadIdx.x;
    float s = 0.f;
    for (int p = 0; p < np; ++p)
        s += partial2[(size_t)p * FEAT + j];
    mean[j] = s / (float)C_CLASSES;
}

// ---------------- Kernel C: per-x-row loss terms (one wave per row) ----------------
__global__ void __launch_bounds__(256) row_loss(
    const float* __restrict__ x,
    const int*   __restrict__ labels,
    const float* __restrict__ centers,
    const float* __restrict__ mean,
    float* __restrict__ lpart)          // [gridDim.x * 2]
{
    const int wid = threadIdx.x >> 6;
    const int ln  = threadIdx.x & 63;
    const int row = blockIdx.x * 4 + wid;

    const float4* __restrict__ xr = reinterpret_cast<const float4*>(x + (size_t)row * FEAT);
    const float4* __restrict__ mr = reinterpret_cast<const float4*>(mean);
    const int lab = labels[row];
    const float4* __restrict__ cr = reinterpret_cast<const float4*>(centers + (size_t)lab * FEAT);

    float ssx = 0.f, dxm = 0.f, ssc = 0.f, dxc = 0.f;
    #pragma unroll
    for (int k = 0; k < 2; ++k) {
        const float4 xv = xr[ln * 2 + k];
        const float4 mv = mr[ln * 2 + k];
        const float4 cv = cr[ln * 2 + k];
        ssx += xv.x * xv.x + xv.y * xv.y + xv.z * xv.z + xv.w * xv.w;
        dxm += xv.x * mv.x + xv.y * mv.y + xv.z * mv.z + xv.w * mv.w;
        ssc += cv.x * cv.x + cv.y * cv.y + cv.z * cv.z + cv.w * cv.w;
        dxc += xv.x * cv.x + xv.y * cv.y + xv.z * cv.z + xv.w * cv.w;
    }

    #pragma unroll
    for (int o = 32; o > 0; o >>= 1) {
        ssx += __shfl_down(ssx, o, 64);
        dxm += __shfl_down(dxm, o, 64);
        ssc += __shfl_down(ssc, o, 64);
        dxc += __shfl_down(dxc, o, 64);
    }

    __shared__ float t1s[4], t2s[4];
    if (ln == 0) {
        const float rnx = 1.f / fmaxf(sqrtf(ssx), EPS_N);
        const float rnc = 1.f / fmaxf(sqrtf(ssc), EPS_N);
        const float s_all = dxm * rnx;
        const float s_lab = dxc * rnx * rnc;
        const float e_all = expf(s_all);
        const float kC    = (float)((double)(C_CLASSES + 1) / (double)C_CLASSES);
        const float t1 = (e_all - expf(s_lab * kC));                        // / ALPHA1 (=1)
        const float t2 = -fabsf((e_all - expf(s_lab) + 0.2f) * (1.f / 50.f));
        t1s[wid] = t1;
        t2s[wid] = t2;
    }
    __syncthreads();
    if (threadIdx.x == 0) {
        lpart[(size_t)blockIdx.x * 2]     = t1s[0] + t1s[1] + t1s[2] + t1s[3];
        lpart[(size_t)blockIdx.x * 2 + 1] = t2s[0] + t2s[1] + t2s[2] + t2s[3];
    }
}

// ---------------- Kernel D: final reduction + blend ----------------
__global__ void final_loss(const float* __restrict__ lpart, int n,
                           const int* __restrict__ epoch,
                           float* __restrict__ out)
{
    __shared__ double sh1[256];
    __shared__ double sh2[256];
    double s1 = 0.0, s2 = 0.0;
    for (int i = threadIdx.x; i < n; i += blockDim.x) {
        s1 += (double)lpart[(size_t)i * 2];
        s2 += (double)lpart[(size_t)i * 2 + 1];
    }
    sh1[threadIdx.x] = s1;
    sh2[threadIdx.x] = s2;
    __syncthreads();
    for (int s = 128; s > 0; s >>= 1) {
        if (threadIdx.x < s) {
            sh1[threadIdx.x] += sh1[threadIdx.x + s];
            sh2[threadIdx.x] += sh2[threadIdx.x + s];
        }
        __syncthreads();
    }
    if (threadIdx.x == 0) {
        const float v  = fminf((float)(*epoch) * (1.f / 14.f), 1.f);
        const float l1 = (float)(sh1[0] / (double)BATCH_N);
        const float l2 = (float)(sh2[0] / (double)BATCH_N);
        out[0] = (1.f - v) * l1 + v * l2;
    }
}

extern "C" void kernel_launch(void* const* d_in, const int* in_sizes, int n_in,
                              void* d_out, int out_size, void* d_ws, size_t ws_size,
                              hipStream_t stream)
{
    const float* x       = (const float*)d_in[0];
    const int*   labels  = (const int*)d_in[1];
    // d_in[2] = ori_labels (unused by reference)
    const int*   epoch   = (const int*)d_in[3];
    const float* centers = (const float*)d_in[4];
    float* out = (float*)d_out;

    float* ws       = (float*)d_ws;
    float* mean     = ws;                       // 512 floats
    float* partial2 = ws + 512;                 // 32*512 = 16384 floats
    float* lpart    = ws + 512 + 16384;         // (BATCH_N/4)*2 = 16384 floats
    float* cpart    = ws + 512 + 16384 + 16384; // nblkA * 512 floats

    const size_t fixed_bytes = (size_t)(512 + 16384 + 16384) * sizeof(float);
    int nblkA = 2048;
    if (ws_size < fixed_bytes + (size_t)nblkA * FEAT * sizeof(float)) {
        size_t avail = (ws_size > fixed_bytes) ? (ws_size - fixed_bytes) : 0;
        nblkA = (int)(avail / (FEAT * sizeof(float)));
        if (nblkA < 1) nblkA = 1;
    }

    centers_pass<<<nblkA, 256, 0, stream>>>(centers, out + 1, cpart);
    reduce_mean_s1<<<32, 512, 0, stream>>>(cpart, nblkA, partial2);
    reduce_mean_s2<<<1, 512, 0, stream>>>(partial2, 32, mean);
    row_loss<<<BATCH_N / 4, 256, 0, stream>>>(x, labels, centers, mean, lpart);
    final_loss<<<1, 256, 0, stream>>>(lpart, BATCH_N / 4, epoch, out);
}